// Round 18
// baseline (275.253 us; speedup 1.0000x reference)
//
#include <hip/hip_runtime.h>

#define DIM   128
#define DMASK 127
#define PLANE (DIM * DIM)     // 16384
#define VOX   (1 << 21)       // 128^3
#define NCH   12

typedef __attribute__((ext_vector_type(2))) _Float16 half2v;

// Per-channel shift pairs (d,h,w) = 2*(one_hot_idx - 1); verified (absmax 0).
__constant__ int c_sd1[12] = { 0, 0, 0, 0, 0, 2, 2, 2, 0, 0, 0, 0};
__constant__ int c_sh1[12] = { 0,-2,-2, 0, 0, 0, 0, 0, 2, 2, 2, 2};
__constant__ int c_sw1[12] = {-2, 0, 0, 2, 2, 0, 0, 0, 0, 0, 0, 0};
__constant__ int c_sd2[12] = {-2,-2, 0,-2, 0, 0, 0, 0,-2, 0, 0, 2};
__constant__ int c_sh2[12] = { 0, 0, 0, 0,-2, 0,-2, 0, 0, 0, 0, 0};
__constant__ int c_sw2[12] = { 0, 0,-2, 0, 0,-2, 0, 2, 0,-2, 2, 0};

__device__ __forceinline__ int clamp7(int v) { return min(max(v, 0), DMASK); }

// FMEGA: the whole MIND-SSC loss in one kernel. Block = 12 waves = 12
// channels; tile = 8 rows x 128 cols x 8 output planes. Each wave runs the
// r15-validated T-plane pipeline (float2 loads + lane shuffles) for BOTH
// images, ssd = fp32 sum of 5 fp16 hist slots -> LDS; 512 threads then do
// the per-voxel min/mean/exp/MSE from LDS. No S array in HBM at all.
// No clip (validated r6-r17). 2 barriers per output plane, wave-symmetric.
__global__ __launch_bounds__(768, 3) void fmega(const float* __restrict__ img0,
                                                const float* __restrict__ img1,
                                                float* __restrict__ partial) {
    int bx = blockIdx.x;            // 256 = 16 hs * 16 ds
    int h0 = (bx & 15) << 3;
    int d0 = (bx >> 4) << 3;
    int tid = threadIdx.x;
    int w  = tid >> 6;              // wave = channel 0..11
    int l  = tid & 63;

    __shared__ _Float16 sbuf[24 * 1024];   // [ch][img][8*128] halves, 48 KB
    __shared__ float rsm[12];

    int sd1 = c_sd1[w], sh1 = c_sh1[w], sw1 = c_sw1[w];
    int sd2 = c_sd2[w], sh2 = c_sh2[w], sw2 = c_sw2[w];

    // wave-uniform row byte-offsets (double clamp composed), 12 rows
    int rowOffA[12], rowOffB[12];
#pragma unroll
    for (int r = 0; r < 12; ++r) {
        int hq = clamp7(h0 - 2 + r);
        rowOffA[r] = clamp7(hq + sh1) * (DIM * 4);
        rowOffB[r] = clamp7(hq + sh2) * (DIM * 4);
    }

    // per-lane column byte bases (float2 at cols 2l+sw, clamped to [0,126])
    int c2 = l << 1;
    int colA = min(max(c2 + sw1, 0), 126) * 4;
    int colB = min(max(c2 + sw2, 0), 126) * 4;
    bool fixAlo = (sw1 < 0) && (l == 0);
    bool fixAhi = (sw1 > 0) && (l == 63);
    bool fixBlo = (sw2 < 0) && (l == 0);
    bool fixBhi = (sw2 > 0) && (l == 63);

    half2v hist[2][5][8];              // 80 VGPRs: 5-plane fp16 window, 2 imgs
#pragma unroll
    for (int i = 0; i < 2; ++i)
#pragma unroll
        for (int s = 0; s < 5; ++s)
#pragma unroll
            for (int k = 0; k < 8; ++k)
                hist[i][s][k] = half2v{(_Float16)0.0f, (_Float16)0.0f};

    const char* ic[2] = { (const char*)img0, (const char*)img1 };
    float acc = 0.0f;

#pragma unroll
    for (int it = 0; it < 12; ++it) {          // 8 outputs + 4 halo planes
        const int s5 = it % 5;                 // static hist slot
        int dp = clamp7(d0 - 2 + it);
        int pOffA = clamp7(dp + sd1) * (PLANE * 4);
        int pOffB = clamp7(dp + sd2) * (PLANE * 4);

#pragma unroll
        for (int i = 0; i < 2; ++i) {
            const char* im = ic[i];
            float tX[12], tY[12];
#pragma unroll
            for (int r = 0; r < 12; ++r) {
                float2 a = *(const float2*)(im + (pOffA + rowOffA[r] + colA));
                float2 b = *(const float2*)(im + (pOffB + rowOffB[r] + colB));
                a.y = fixAlo ? a.x : a.y;  a.x = fixAhi ? a.y : a.x;
                b.y = fixBlo ? b.x : b.y;  b.x = fixBhi ? b.y : b.x;
                float dx = a.x - b.x; dx *= dx;      // D2[2l]
                float dy = a.y - b.y; dy *= dy;      // D2[2l+1]
                float lx = __shfl_up(dx, 1, 64);     // D2[2l-2]
                float ly = __shfl_up(dy, 1, 64);     // D2[2l-1]
                float rx = __shfl_down(dx, 1, 64);   // D2[2l+2]
                float ry = __shfl_down(dy, 1, 64);   // D2[2l+3]
                ly = (l == 0)  ? dx : ly;            // D2[-1 -> 0]
                rx = (l == 63) ? dy : rx;            // D2[128 -> 127]
                tX[r] = lx + ly + dx + dy + rx;      // W-box(2l)
                tY[r] = ly + dx + dy + rx + ry;      // W-box(2l+1)
            }
            // H-box sliding 5-row sums -> fp16 hist slot
            float sx = tX[0] + tX[1] + tX[2] + tX[3] + tX[4];
            float sy = tY[0] + tY[1] + tY[2] + tY[3] + tY[4];
#pragma unroll
            for (int k = 0; k < 8; ++k) {
                hist[i][s5][k] = half2v{ (_Float16)sx, (_Float16)sy };
                if (k < 7) {
                    sx += tX[k + 5] - tX[k];
                    sy += tY[k + 5] - tY[k];
                }
            }
        }

        if (it >= 4) {
            // ssd = fp32 sum of the 5 fp16 window slots -> fp16 -> LDS
#pragma unroll
            for (int i = 0; i < 2; ++i) {
                half2v* dst = (half2v*)sbuf + ((w << 1) + i) * 512 + l;
#pragma unroll
                for (int k = 0; k < 8; ++k) {
                    float wx = 0.0f, wy = 0.0f;
#pragma unroll
                    for (int s = 0; s < 5; ++s) {
                        wx += (float)hist[i][s][k][0];
                        wy += (float)hist[i][s][k][1];
                    }
                    dst[k * 64] = half2v{ (_Float16)wx, (_Float16)wy };
                }
            }
            __syncthreads();

            if (tid < 512) {                   // 2 voxels/thread, 1024 vox
                half2v sA[NCH], sB[NCH];
#pragma unroll
                for (int ch = 0; ch < NCH; ++ch) {
                    sA[ch] = ((half2v*)sbuf)[((ch << 1) + 0) * 512 + tid];
                    sB[ch] = ((half2v*)sbuf)[((ch << 1) + 1) * 512 + tid];
                }
                float mnA0 = 3.4e38f, smA0 = 0.0f, mnA1 = 3.4e38f, smA1 = 0.0f;
                float mnB0 = 3.4e38f, smB0 = 0.0f, mnB1 = 3.4e38f, smB1 = 0.0f;
#pragma unroll
                for (int ch = 0; ch < NCH; ++ch) {
                    float a0 = (float)sA[ch][0], a1 = (float)sA[ch][1];
                    float b0 = (float)sB[ch][0], b1 = (float)sB[ch][1];
                    mnA0 = fminf(mnA0, a0); smA0 += a0;
                    mnA1 = fminf(mnA1, a1); smA1 += a1;
                    mnB0 = fminf(mnB0, b0); smB0 += b0;
                    mnB1 = fminf(mnB1, b1); smB1 += b1;
                }
                float iA0 = __fdividef(1.0f, smA0 * (1.0f / 12.0f) - mnA0);
                float iA1 = __fdividef(1.0f, smA1 * (1.0f / 12.0f) - mnA1);
                float iB0 = __fdividef(1.0f, smB0 * (1.0f / 12.0f) - mnB0);
                float iB1 = __fdividef(1.0f, smB1 * (1.0f / 12.0f) - mnB1);
#pragma unroll
                for (int ch = 0; ch < NCH; ++ch) {
                    float e00 = __expf(-((float)sA[ch][0] - mnA0) * iA0);
                    float e10 = __expf(-((float)sB[ch][0] - mnB0) * iB0);
                    float df0 = e00 - e10; acc += df0 * df0;
                    float e01 = __expf(-((float)sA[ch][1] - mnA1) * iA1);
                    float e11 = __expf(-((float)sB[ch][1] - mnB1) * iB1);
                    float df1 = e01 - e11; acc += df1 * df1;
                }
            }
            __syncthreads();
        }
    }

    // block reduction: 12 waves -> rsm -> thread 0
#pragma unroll
    for (int off = 32; off > 0; off >>= 1)
        acc += __shfl_down(acc, off, 64);
    if (l == 0) rsm[w] = acc;
    __syncthreads();
    if (tid == 0) {
        float t = 0.0f;
#pragma unroll
        for (int i = 0; i < 12; ++i) t += rsm[i];
        partial[bx] = t;
    }
}

// kred: sum 256 partials, write the final scalar.
__global__ __launch_bounds__(256) void kred(const float* __restrict__ partial,
                                            float* __restrict__ out) {
    int tid = threadIdx.x;
    float acc = partial[tid];
#pragma unroll
    for (int off = 32; off > 0; off >>= 1)
        acc += __shfl_down(acc, off, 64);
    __shared__ float smem[4];
    int lane = tid & 63, wv = tid >> 6;
    if (lane == 0) smem[wv] = acc;
    __syncthreads();
    if (tid == 0)
        out[0] = (smem[0] + smem[1] + smem[2] + smem[3])
               * (1.0f / (12.0f * (float)VOX));
}

__global__ void kdiag(float* out, float ws_mb) { out[0] = ws_mb; }

extern "C" void kernel_launch(void* const* d_in, const int* in_sizes, int n_in,
                              void* d_out, int out_size, void* d_ws, size_t ws_size,
                              hipStream_t stream) {
    const float* y_true = (const float*)d_in[0];
    const float* y_pred = (const float*)d_in[1];
    float* out = (float*)d_out;

    const size_t NEED = 4096;
    if (ws_size < NEED) {
        kdiag<<<1, 1, 0, stream>>>(out, (float)(ws_size >> 20));
        return;
    }

    float* partial = (float*)d_ws;    // 256 floats

    fmega<<<256, 768, 0, stream>>>(y_true, y_pred, partial);
    kred <<<1, 256, 0, stream>>>(partial, out);
}

// Round 19
// 233.036 us; speedup vs baseline: 1.1812x; 1.1812x over previous
//
#include <hip/hip_runtime.h>

#define DIM   128
#define DMASK 127
#define PLANE (DIM * DIM)     // 16384
#define VOX   (1 << 21)       // 128^3
#define NCH   12

// De-aliased channel-major layout (validated r12/r15): ch stride 4MB+4KB,
// image stride +2KB more.
#define CHS   (VOX + 2048)
#define IMGS  (NCH * CHS + 1024)

typedef __attribute__((ext_vector_type(2))) _Float16 half2v;
typedef __attribute__((ext_vector_type(4))) _Float16 half4v;

// Per-channel shift pairs (d,h,w) = 2*(one_hot_idx - 1); verified (absmax 0).
__constant__ int c_sd1[12] = { 0, 0, 0, 0, 0, 2, 2, 2, 0, 0, 0, 0};
__constant__ int c_sh1[12] = { 0,-2,-2, 0, 0, 0, 0, 0, 2, 2, 2, 2};
__constant__ int c_sw1[12] = {-2, 0, 0, 2, 2, 0, 0, 0, 0, 0, 0, 0};
__constant__ int c_sd2[12] = {-2,-2, 0,-2, 0, 0, 0, 0,-2, 0, 0, 2};
__constant__ int c_sh2[12] = { 0, 0, 0, 0,-2, 0,-2, 0, 0, 0, 0, 0};
__constant__ int c_sw2[12] = { 0, 0,-2, 0, 0,-2, 0, 2, 0,-2, 2, 0};

__device__ __forceinline__ int clamp7(int v) { return min(max(v, 0), DMASK); }

// F123 v7: wave-autonomous (r15 pipeline), occupancy-sized for 6 blocks/CU:
//  - 4-row h-slices: hist[5][4]=20 regs, tX/tY[8]=16 (r15: 40+24)
//  - win[] dropped: ssd recomputed as the 5-slot sum at write time
//  - state ~60 VGPR, fits the 85-reg cap at launch_bounds(256,6)
//    (r16 spilled because hist[5][8]+win+tX/tY[12] ~ 96 > 85)
// Spill tripwire: WRITE_SIZE must stay 98 MB.
__global__ __launch_bounds__(256, 6) void f123(const float* __restrict__ img0,
                                               const float* __restrict__ img1,
                                               _Float16* __restrict__ Sall) {
    const float* img = blockIdx.y ? img1 : img0;
    _Float16* outS = Sall + (size_t)blockIdx.y * IMGS;
    const char* imgc = (const char*)img;

    int wid = (blockIdx.x << 2) + (threadIdx.x >> 6);  // 0..3071
    int ch = wid >> 8;                 // 12
    int hs = (wid >> 3) & 31;          // 32 h-slices of 4 rows
    int ds = wid & 7;                  // 8 d-segs of 16 planes
    int h0 = hs << 2;
    int d0 = ds << 4;
    int l  = threadIdx.x & 63;

    int sd1 = c_sd1[ch], sh1 = c_sh1[ch], sw1 = c_sw1[ch];
    int sd2 = c_sd2[ch], sh2 = c_sh2[ch], sw2 = c_sw2[ch];

    // wave-uniform row byte-offsets (double clamp composed), 8 rows
    int rowOffA[8], rowOffB[8];
#pragma unroll
    for (int r = 0; r < 8; ++r) {
        int hq = clamp7(h0 - 2 + r);
        rowOffA[r] = clamp7(hq + sh1) * (DIM * 4);
        rowOffB[r] = clamp7(hq + sh2) * (DIM * 4);
    }

    // per-lane column byte bases (float2 at cols 2l+sw, clamped to [0,126])
    int c2 = l << 1;
    int colA = min(max(c2 + sw1, 0), 126) * 4;
    int colB = min(max(c2 + sw2, 0), 126) * 4;
    bool fixAlo = (sw1 < 0) && (l == 0);   // need (v0,v0): a.y = a.x
    bool fixAhi = (sw1 > 0) && (l == 63);  // need (v127,v127): a.x = a.y
    bool fixBlo = (sw2 < 0) && (l == 0);
    bool fixBhi = (sw2 > 0) && (l == 63);

    half2v hist[5][4];                 // 5-plane fp16 window, 4 rows
#pragma unroll
    for (int s = 0; s < 5; ++s)
#pragma unroll
        for (int k = 0; k < 4; ++k)
            hist[s][k] = half2v{(_Float16)0.0f, (_Float16)0.0f};

    _Float16* dstBase = outS + (size_t)ch * CHS + h0 * DIM + c2;

    for (int oo = 0; oo < 4; ++oo) {
#pragma unroll
        for (int s5 = 0; s5 < 5; ++s5) {
            int it = oo * 5 + s5;
            int dp = clamp7(d0 - 2 + it);
            int pOffA = clamp7(dp + sd1) * (PLANE * 4);
            int pOffB = clamp7(dp + sd2) * (PLANE * 4);

            float tX[8], tY[8];
#pragma unroll
            for (int r = 0; r < 8; ++r) {
                float2 a = *(const float2*)(imgc + (pOffA + rowOffA[r] + colA));
                float2 b = *(const float2*)(imgc + (pOffB + rowOffB[r] + colB));
                a.y = fixAlo ? a.x : a.y;  a.x = fixAhi ? a.y : a.x;
                b.y = fixBlo ? b.x : b.y;  b.x = fixBhi ? b.y : b.x;
                float dx = a.x - b.x; dx *= dx;      // D2[2l]
                float dy = a.y - b.y; dy *= dy;      // D2[2l+1]
                float lx = __shfl_up(dx, 1, 64);     // D2[2l-2]
                float ly = __shfl_up(dy, 1, 64);     // D2[2l-1]
                float rx = __shfl_down(dx, 1, 64);   // D2[2l+2]
                float ry = __shfl_down(dy, 1, 64);   // D2[2l+3]
                ly = (l == 0)  ? dx : ly;            // D2[-1 -> 0]
                rx = (l == 63) ? dy : rx;            // D2[128 -> 127]
                tX[r] = lx + ly + dx + dy + rx;      // W-box(2l)
                tY[r] = ly + dx + dy + rx + ry;      // W-box(2l+1)
            }

            // H-box sliding 5-row sums -> hist slot; write ssd = 5-slot sum
            float sx = tX[0] + tX[1] + tX[2] + tX[3] + tX[4];
            float sy = tY[0] + tY[1] + tY[2] + tY[3] + tY[4];
            bool dowrite = (it >= 4);
            _Float16* dstD = dstBase + (size_t)(d0 + it - 4) * PLANE;
#pragma unroll
            for (int k = 0; k < 4; ++k) {
                hist[s5][k] = half2v{ (_Float16)sx, (_Float16)sy };  // round first
                if (dowrite) {
                    float wx = 0.0f, wy = 0.0f;
#pragma unroll
                    for (int s = 0; s < 5; ++s) {
                        wx += (float)hist[s][k][0];
                        wy += (float)hist[s][k][1];
                    }
                    half2v ov = { (_Float16)wx, (_Float16)wy };
                    *(half2v*)(dstD + k * DIM) = ov;
                }
                if (k < 3) {
                    sx += tX[k + 5] - tX[k];
                    sy += tY[k + 5] - tY[k];
                }
            }
        }
    }
}

// kmse v6 (exact r15, validated): 4 vox/thread, 24 independent 8-B loads,
// all-register, no atomics, de-aliased CHS stride.
__global__ __launch_bounds__(256, 3) void kmse(const _Float16* __restrict__ S0,
                                               const _Float16* __restrict__ S1,
                                               float* __restrict__ partial) {
    int t = blockIdx.x * 256 + threadIdx.x;       // 2048 blocks

    half4v v0[NCH], v1[NCH];
#pragma unroll
    for (int ch = 0; ch < NCH; ++ch)
        v0[ch] = ((const half4v*)(S0 + (size_t)ch * CHS))[t];
#pragma unroll
    for (int ch = 0; ch < NCH; ++ch)
        v1[ch] = ((const half4v*)(S1 + (size_t)ch * CHS))[t];

    float mn0[4], sm0[4], mn1[4], sm1[4];
#pragma unroll
    for (int j = 0; j < 4; ++j) {
        mn0[j] = 3.4e38f; sm0[j] = 0.0f;
        mn1[j] = 3.4e38f; sm1[j] = 0.0f;
    }
#pragma unroll
    for (int ch = 0; ch < NCH; ++ch)
#pragma unroll
        for (int j = 0; j < 4; ++j) {
            float s0 = (float)v0[ch][j];
            float s1 = (float)v1[ch][j];
            mn0[j] = fminf(mn0[j], s0); sm0[j] += s0;
            mn1[j] = fminf(mn1[j], s1); sm1[j] += s1;
        }

    float inv0[4], inv1[4];
#pragma unroll
    for (int j = 0; j < 4; ++j) {
        inv0[j] = __fdividef(1.0f, sm0[j] * (1.0f / 12.0f) - mn0[j]);
        inv1[j] = __fdividef(1.0f, sm1[j] * (1.0f / 12.0f) - mn1[j]);
    }

    float acc = 0.0f;
#pragma unroll
    for (int ch = 0; ch < NCH; ++ch)
#pragma unroll
        for (int j = 0; j < 4; ++j) {
            float e0 = __expf(-((float)v0[ch][j] - mn0[j]) * inv0[j]);
            float e1 = __expf(-((float)v1[ch][j] - mn1[j]) * inv1[j]);
            float df = e0 - e1;
            acc += df * df;
        }

#pragma unroll
    for (int off = 32; off > 0; off >>= 1)
        acc += __shfl_down(acc, off, 64);
    __shared__ float smem[4];
    int lane = threadIdx.x & 63, wv = threadIdx.x >> 6;
    if (lane == 0) smem[wv] = acc;
    __syncthreads();
    if (threadIdx.x == 0)
        partial[blockIdx.x] = smem[0] + smem[1] + smem[2] + smem[3];
}

// kred: sum 2048 partials, write the final scalar.
__global__ __launch_bounds__(256) void kred(const float* __restrict__ partial,
                                            float* __restrict__ out) {
    int tid = threadIdx.x;
    float acc = 0.0f;
#pragma unroll
    for (int k = 0; k < 8; ++k)
        acc += partial[tid + (k << 8)];
#pragma unroll
    for (int off = 32; off > 0; off >>= 1)
        acc += __shfl_down(acc, off, 64);
    __shared__ float smem[4];
    int lane = tid & 63, wv = tid >> 6;
    if (lane == 0) smem[wv] = acc;
    __syncthreads();
    if (tid == 0)
        out[0] = (smem[0] + smem[1] + smem[2] + smem[3])
               * (1.0f / (12.0f * (float)VOX));
}

__global__ void kdiag(float* out, float ws_mb) { out[0] = ws_mb; }

extern "C" void kernel_launch(void* const* d_in, const int* in_sizes, int n_in,
                              void* d_out, int out_size, void* d_ws, size_t ws_size,
                              hipStream_t stream) {
    const float* y_true = (const float*)d_in[0];
    const float* y_pred = (const float*)d_in[1];
    float* out = (float*)d_out;

    const size_t NEED = 2ull * IMGS * sizeof(_Float16) + 8192 + 64;  // ~96.2 MB
    if (ws_size < NEED) {
        kdiag<<<1, 1, 0, stream>>>(out, (float)(ws_size >> 20));
        return;
    }

    _Float16* S0      = (_Float16*)d_ws;            // ssd img0 (CHS layout)
    _Float16* S1      = S0 + (size_t)IMGS;          // ssd img1
    float*    partial = (float*)(S1 + (size_t)IMGS);// 2048 floats

    // 3072 wave-tasks per image (12 ch x 32 hslices x 8 dsegs), 4 waves/block
    f123<<<dim3(768, 2), 256, 0, stream>>>(y_true, y_pred, S0);
    kmse<<<VOX / 4 / 256, 256, 0, stream>>>(S0, S1, partial);
    kred<<<1, 256, 0, stream>>>(partial, out);
}